// Round 2
// baseline (413.546 us; speedup 1.0000x reference)
//
#include <hip/hip_runtime.h>

// SceneContraction: means = contract(mean); cov_out = J cov J^T for ||mean||>=1,
// else passthrough.  J = s*I + c*x x^T (symmetric), s = 2/r - 1/r^2,
// c = 2(1-r)/r^4.  Branch-free: r<1 => select s=1, c=0 => J=I => passthrough
// falls out of the same code path (no divergence).
//
// Round-2 structure: no LDS, no barriers. Each thread owns 4 contiguous
// samples so every global access is a float4 (3 mean-vec4 + 9 cov-vec4 loads,
// 12 vec4 stores). 192 B of loads in flight per thread for MLP. Memory-bound:
// 402.7 MB total -> ~64 us at 6.3 TB/s achievable.

#define BLOCK 256

union F12 { float4 v[3]; float f[12]; };
union F36 { float4 v[9]; float f[36]; };

__device__ __forceinline__ void contract_one(
    float x, float y, float z,
    const float* __restrict__ e,   // 9 cov entries, row-major
    float* __restrict__ om,        // 3 out mean
    float* __restrict__ oc)        // 9 out cov
{
    const float r2 = fmaf(x, x, fmaf(y, y, z * z));
    const float r  = sqrtf(r2);
    const float inv = 1.0f / r;                 // inf if r==0 (discarded below)
    float s  = (2.0f - inv) * inv;              // 2/r - 1/r^2
    const float inv2 = inv * inv;
    float cc = 2.0f * (1.0f - r) * (inv2 * inv2);  // 2(1-r)/r^4

    const bool inside = r < 1.0f;
    s  = inside ? 1.0f : s;                     // J = I  => passthrough
    cc = inside ? 0.0f : cc;

    // symmetric Jacobian J = s*I + cc * x x^T
    const float j00 = fmaf(cc * x, x, s);
    const float j01 = cc * x * y;
    const float j02 = cc * x * z;
    const float j11 = fmaf(cc * y, y, s);
    const float j12 = cc * y * z;
    const float j22 = fmaf(cc * z, z, s);

    om[0] = s * x;
    om[1] = s * y;
    om[2] = s * z;

    // T = J * C
    const float t00 = j00 * e[0] + j01 * e[3] + j02 * e[6];
    const float t01 = j00 * e[1] + j01 * e[4] + j02 * e[7];
    const float t02 = j00 * e[2] + j01 * e[5] + j02 * e[8];
    const float t10 = j01 * e[0] + j11 * e[3] + j12 * e[6];
    const float t11 = j01 * e[1] + j11 * e[4] + j12 * e[7];
    const float t12 = j01 * e[2] + j11 * e[5] + j12 * e[8];
    const float t20 = j02 * e[0] + j12 * e[3] + j22 * e[6];
    const float t21 = j02 * e[1] + j12 * e[4] + j22 * e[7];
    const float t22 = j02 * e[2] + j12 * e[5] + j22 * e[8];

    // O = T * J^T = T * J (J symmetric)
    oc[0] = t00 * j00 + t01 * j01 + t02 * j02;
    oc[1] = t00 * j01 + t01 * j11 + t02 * j12;
    oc[2] = t00 * j02 + t01 * j12 + t02 * j22;
    oc[3] = t10 * j00 + t11 * j01 + t12 * j02;
    oc[4] = t10 * j01 + t11 * j11 + t12 * j12;
    oc[5] = t10 * j02 + t11 * j12 + t12 * j22;
    oc[6] = t20 * j00 + t21 * j01 + t22 * j02;
    oc[7] = t20 * j01 + t21 * j11 + t22 * j12;
    oc[8] = t20 * j02 + t21 * j12 + t22 * j22;
}

__global__ __launch_bounds__(BLOCK) void scene_contraction_kernel(
    const float* __restrict__ mean,
    const float* __restrict__ cov,
    float* __restrict__ out_mean,
    float* __restrict__ out_cov,
    int N)
{
    const long long t  = (long long)blockIdx.x * BLOCK + threadIdx.x;  // 4-sample chunk id
    const long long s0 = t * 4;
    if (s0 >= N) return;

    if (s0 + 4 <= N) {
        // ---- fast path: all-vec4 loads ----
        F12 m;  F36 c;
        const float4* mg = (const float4*)mean + t * 3;
        const float4* cg = (const float4*)cov  + t * 9;
        #pragma unroll
        for (int i = 0; i < 3; ++i) m.v[i] = mg[i];
        #pragma unroll
        for (int i = 0; i < 9; ++i) c.v[i] = cg[i];

        F12 om; F36 oc;
        #pragma unroll
        for (int k = 0; k < 4; ++k)
            contract_one(m.f[3*k], m.f[3*k+1], m.f[3*k+2],
                         &c.f[9*k], &om.f[3*k], &oc.f[9*k]);

        float4* omg = (float4*)out_mean + t * 3;
        float4* ocg = (float4*)out_cov  + t * 9;
        #pragma unroll
        for (int i = 0; i < 3; ++i) omg[i] = om.v[i];
        #pragma unroll
        for (int i = 0; i < 9; ++i) ocg[i] = oc.v[i];
    } else {
        // ---- tail: scalar per-sample (unreachable for N % 4 == 0) ----
        for (long long sidx = s0; sidx < N; ++sidx) {
            float e[9], om[3], oc[9];
            #pragma unroll
            for (int i = 0; i < 9; ++i) e[i] = cov[sidx * 9 + i];
            contract_one(mean[sidx * 3], mean[sidx * 3 + 1], mean[sidx * 3 + 2],
                         e, om, oc);
            #pragma unroll
            for (int i = 0; i < 3; ++i) out_mean[sidx * 3 + i] = om[i];
            #pragma unroll
            for (int i = 0; i < 9; ++i) out_cov[sidx * 9 + i] = oc[i];
        }
    }
}

extern "C" void kernel_launch(void* const* d_in, const int* in_sizes, int n_in,
                              void* d_out, int out_size, void* d_ws, size_t ws_size,
                              hipStream_t stream) {
    const float* mean = (const float*)d_in[0];
    const float* cov  = (const float*)d_in[1];
    float* out        = (float*)d_out;

    const int N = in_sizes[0] / 3;          // 4,194,304
    float* out_mean = out;
    float* out_cov  = out + (size_t)N * 3;

    const long long nthreads = ((long long)N + 3) / 4;
    const int blocks = (int)((nthreads + BLOCK - 1) / BLOCK);
    hipLaunchKernelGGL(scene_contraction_kernel, dim3(blocks), dim3(BLOCK), 0, stream,
                       mean, cov, out_mean, out_cov, N);
}

// Round 4
// 313.575 us; speedup vs baseline: 1.3188x; 1.3188x over previous
//
#include <hip/hip_runtime.h>

// SceneContraction: means = contract(mean); cov_out = J cov J^T for ||mean||>=1,
// else passthrough.  J = s*I + c*x x^T (symmetric), s = 2/r - 1/r^2,
// c = 2(1-r)/r^4.  Branch-free: r<1 => s=1, c=0 => J=I => passthrough.
//
// Round-4 = round-3 with the compile fix: __builtin_nontemporal_* needs a
// native clang vector type, not HIP_vector_type<float,4>. Use ext_vector f4.
//
// Structure: WAVE-PRIVATE LDS staging, no __syncthreads.
//  - Each wave owns 64 contiguous samples; stages mean(48 f4)+cov(144 f4)
//    through its own 3 KB LDS region with per-instruction-contiguous float4
//    accesses (round 2 proved strided vec4 collapses HBM to 2.9 TB/s).
//  - Wave-synchronous LDS: in-order LDS pipe per wave + wave_barrier/clobber
//    instead of 2x s_barrier -> waves pipeline independently.
//  - Nontemporal loads/stores: 403 MB streams with zero reuse; don't thrash L2.
// Memory-bound: 402.7 MB -> ~67-73 us at realistic mixed-stream BW.

#define BLOCK 256
#define WAVE  64

typedef float f4 __attribute__((ext_vector_type(4)));   // native vector for nt builtins

__device__ __forceinline__ void wave_fence() {
    __builtin_amdgcn_wave_barrier();     // scheduler fence (no HW cost)
    asm volatile("" ::: "memory");       // compiler memory fence
}

__device__ __forceinline__ void contract_one(
    float x, float y, float z,
    const float* __restrict__ e,   // 9 cov entries, row-major
    float* __restrict__ om,        // 3 out mean
    float* __restrict__ oc)        // 9 out cov
{
    const float r2 = fmaf(x, x, fmaf(y, y, z * z));
    const float r  = sqrtf(r2);
    const float inv = 1.0f / r;                 // inf if r==0 (discarded below)
    float s  = (2.0f - inv) * inv;              // 2/r - 1/r^2
    const float inv2 = inv * inv;
    float cc = 2.0f * (1.0f - r) * (inv2 * inv2);  // 2(1-r)/r^4

    const bool inside = r < 1.0f;
    s  = inside ? 1.0f : s;                     // J = I  => passthrough
    cc = inside ? 0.0f : cc;

    // symmetric Jacobian J = s*I + cc * x x^T
    const float j00 = fmaf(cc * x, x, s);
    const float j01 = cc * x * y;
    const float j02 = cc * x * z;
    const float j11 = fmaf(cc * y, y, s);
    const float j12 = cc * y * z;
    const float j22 = fmaf(cc * z, z, s);

    om[0] = s * x;
    om[1] = s * y;
    om[2] = s * z;

    // T = J * C
    const float t00 = j00 * e[0] + j01 * e[3] + j02 * e[6];
    const float t01 = j00 * e[1] + j01 * e[4] + j02 * e[7];
    const float t02 = j00 * e[2] + j01 * e[5] + j02 * e[8];
    const float t10 = j01 * e[0] + j11 * e[3] + j12 * e[6];
    const float t11 = j01 * e[1] + j11 * e[4] + j12 * e[7];
    const float t12 = j01 * e[2] + j11 * e[5] + j12 * e[8];
    const float t20 = j02 * e[0] + j12 * e[3] + j22 * e[6];
    const float t21 = j02 * e[1] + j12 * e[4] + j22 * e[7];
    const float t22 = j02 * e[2] + j12 * e[5] + j22 * e[8];

    // O = T * J^T = T * J (J symmetric)
    oc[0] = t00 * j00 + t01 * j01 + t02 * j02;
    oc[1] = t00 * j01 + t01 * j11 + t02 * j12;
    oc[2] = t00 * j02 + t01 * j12 + t02 * j22;
    oc[3] = t10 * j00 + t11 * j01 + t12 * j02;
    oc[4] = t10 * j01 + t11 * j11 + t12 * j12;
    oc[5] = t10 * j02 + t11 * j12 + t12 * j22;
    oc[6] = t20 * j00 + t21 * j01 + t22 * j02;
    oc[7] = t20 * j01 + t21 * j11 + t22 * j12;
    oc[8] = t20 * j02 + t21 * j12 + t22 * j22;
}

__global__ __launch_bounds__(BLOCK) void scene_contraction_kernel(
    const float* __restrict__ mean,
    const float* __restrict__ cov,
    float* __restrict__ out_mean,
    float* __restrict__ out_cov,
    int N)
{
    __shared__ float lds[BLOCK * 12];   // 12 KB: per-wave 768-float region

    const int tid  = threadIdx.x;
    const int lane = tid & 63;
    const int wv   = tid >> 6;
    const long long waveBase = (long long)blockIdx.x * BLOCK + (long long)wv * WAVE;

    float* wm = lds + wv * 768;         // 192 floats: wave's mean tile
    float* wc = wm + 192;               // 576 floats: wave's cov tile
    f4* sm4 = (f4*)wm;                  // 48 f4
    f4* sc4 = (f4*)wc;                  // 144 f4

    if (waveBase + WAVE <= (long long)N) {
        // ---- stage global -> LDS, per-instruction-contiguous float4 ----
        const f4* gm = (const f4*)(mean + waveBase * 3);   // 48 f4
        const f4* gc = (const f4*)(cov  + waveBase * 9);   // 144 f4

        f4 m0, c0, c1, c2;
        if (lane < 48) m0 = __builtin_nontemporal_load(gm + lane);
        c0 = __builtin_nontemporal_load(gc + lane);
        c1 = __builtin_nontemporal_load(gc + lane + 64);
        if (lane < 16) c2 = __builtin_nontemporal_load(gc + lane + 128);

        if (lane < 48) sm4[lane] = m0;
        sc4[lane]      = c0;
        sc4[lane + 64] = c1;
        if (lane < 16) sc4[lane + 128] = c2;

        wave_fence();

        // ---- per-lane compute (sample = waveBase + lane), in-place LDS ----
        {
            const float x = wm[lane * 3 + 0];
            const float y = wm[lane * 3 + 1];
            const float z = wm[lane * 3 + 2];
            float e[9], om[3], oc[9];
            #pragma unroll
            for (int i = 0; i < 9; ++i) e[i] = wc[lane * 9 + i];

            contract_one(x, y, z, e, om, oc);

            wm[lane * 3 + 0] = om[0];
            wm[lane * 3 + 1] = om[1];
            wm[lane * 3 + 2] = om[2];
            #pragma unroll
            for (int i = 0; i < 9; ++i) wc[lane * 9 + i] = oc[i];
        }

        wave_fence();

        // ---- LDS -> global, nontemporal float4 stores ----
        f4* go_m = (f4*)(out_mean + waveBase * 3);
        f4* go_c = (f4*)(out_cov  + waveBase * 9);
        if (lane < 48) __builtin_nontemporal_store(sm4[lane], go_m + lane);
        __builtin_nontemporal_store(sc4[lane],      go_c + lane);
        __builtin_nontemporal_store(sc4[lane + 64], go_c + lane + 64);
        if (lane < 16) __builtin_nontemporal_store(sc4[lane + 128], go_c + lane + 128);
    } else {
        // ---- tail: scalar per-sample (unreachable for N % 256 == 0) ----
        const long long s = waveBase + lane;
        if (s < (long long)N) {
            float e[9], om[3], oc[9];
            #pragma unroll
            for (int i = 0; i < 9; ++i) e[i] = cov[s * 9 + i];
            contract_one(mean[s * 3], mean[s * 3 + 1], mean[s * 3 + 2], e, om, oc);
            #pragma unroll
            for (int i = 0; i < 3; ++i) out_mean[s * 3 + i] = om[i];
            #pragma unroll
            for (int i = 0; i < 9; ++i) out_cov[s * 9 + i] = oc[i];
        }
    }
}

extern "C" void kernel_launch(void* const* d_in, const int* in_sizes, int n_in,
                              void* d_out, int out_size, void* d_ws, size_t ws_size,
                              hipStream_t stream) {
    const float* mean = (const float*)d_in[0];
    const float* cov  = (const float*)d_in[1];
    float* out        = (float*)d_out;

    const int N = in_sizes[0] / 3;          // 4,194,304
    float* out_mean = out;
    float* out_cov  = out + (size_t)N * 3;

    const int blocks = (N + BLOCK - 1) / BLOCK;
    hipLaunchKernelGGL(scene_contraction_kernel, dim3(blocks), dim3(BLOCK), 0, stream,
                       mean, cov, out_mean, out_cov, N);
}